// Round 11
// baseline (192.405 us; speedup 1.0000x reference)
//
#include <hip/hip_runtime.h>
#include <hip/hip_cooperative_groups.h>
#include <math.h>

namespace cg = cooperative_groups;

#define D_DIM   128
#define NCHART  64
#define PADR    132      // padded row stride (floats); 132*4B = 16B-aligned rows
#define BPC     8        // blocks per chart; 512 blocks = 2/CU (LDS-limited) co-residency
#define NS      2        // samples per wave batch
#define LCAP    256      // per-chart list capacity (mean 64)
#define MAXNORM 0.99f

typedef float f32x4 __attribute__((ext_vector_type(4)));

__device__ __forceinline__ float wave_sum(float v) {
#pragma unroll
  for (int m = 32; m > 0; m >>= 1) v += __shfl_xor(v, m, 64);
  return v;
}

__global__ __launch_bounds__(256) void k_fused(
    const float* __restrict__ z_n, const float* __restrict__ centers,
    const float* __restrict__ rot, const int* __restrict__ src_idx,
    const int* __restrict__ tgt_idx, float* __restrict__ out, int B)
{
  __shared__ float R[D_DIM * PADR];         // 67.6 KB
  __shared__ float zs[4][NS][D_DIM];        // 4 KB
  __shared__ int tlist[LCAP], slist[LCAP];  // 2 KB
  __shared__ int wcT[4], wcS[4];

  cg::grid_group grid = cg::this_grid();
  const int tid = threadIdx.x;
  const int chart = blockIdx.x >> 3;
  const int q = blockIdx.x & 7;
  const int w = tid >> 6, l = tid & 63;

  // ---- stage R(chart) once; reused by both phases (phase B reads columns = R^T)
  const f32x4* G4 = (const f32x4*)(rot + (size_t)chart * D_DIM * D_DIM);
  for (int g = tid; g < 4096; g += 256) {
    int r = g >> 5, J = g & 31;
    *(f32x4*)&R[r * PADR + 4 * J] = G4[g];
  }

  // ---- deterministic index-ordered dual list build (identical across the 8
  // blocks of a chart). Round-10 bug: atomic appends gave each block a different
  // permutation -> slot partition double-/un-covered samples. Ballot+prefix fixes.
  int totT = 0, totS = 0;
  const unsigned long long below = (1ull << l) - 1;   // l in [0,63]
  for (int b0 = 0; b0 < B; b0 += 256) {
    int b = b0 + tid;
    bool mT = (b < B) && (tgt_idx[b] == chart);
    bool mS = (b < B) && (src_idx[b] == chart);
    unsigned long long maskT = __ballot(mT);
    unsigned long long maskS = __ballot(mS);
    if (l == 0) { wcT[w] = __popcll(maskT); wcS[w] = __popcll(maskS); }
    __syncthreads();
    int baseT = totT, baseS = totS;
#pragma unroll
    for (int ww = 0; ww < 4; ++ww) {
      if (ww < w) { baseT += wcT[ww]; baseS += wcS[ww]; }
    }
    int posT = baseT + __popcll(maskT & below);
    int posS = baseS + __popcll(maskS & below);
    if (mT && posT < LCAP) tlist[posT] = b;
    if (mS && posS < LCAP) slist[posS] = b;
    totT += wcT[0] + wcT[1] + wcT[2] + wcT[3];
    totS += wcS[0] + wcS[1] + wcS[2] + wcS[3];
    __syncthreads();
  }
  int n = min(totT, LCAP);

  // ---- phase A: z_global = mobius(-proj(c_src), proj(z)); v = R @ z_global -> out
  // wave-slot = q*4+w in [0,32); starts {0,NS,...}, stride 32*NS -> exact partition
  for (int s0 = (q * 4 + w) * NS; s0 < n; s0 += 32 * NS) {
    const int kmax = min(NS, n - s0);   // wave-uniform
    int bs[NS];
#pragma unroll
    for (int k = 0; k < NS; ++k) {
      if (k < kmax) {
        int b = tlist[s0 + k];
        bs[k] = b;
        float a  = z_n[(size_t)b * D_DIM + l];
        float bb = z_n[(size_t)b * D_DIM + l + 64];
        float nz = sqrtf(wave_sum(a * a + bb * bb));
        if (nz > MAXNORM) { float sc = MAXNORM / nz; a *= sc; bb *= sc; }

        int si = src_idx[b];
        float c0 = centers[(size_t)si * D_DIM + l];
        float c1 = centers[(size_t)si * D_DIM + l + 64];
        float ncn = sqrtf(wave_sum(c0 * c0 + c1 * c1));
        if (ncn > MAXNORM) { float sc = MAXNORM / ncn; c0 *= sc; c1 *= sc; }
        c0 = -c0; c1 = -c1;                        // x = -c_source

        float x2 = wave_sum(c0 * c0 + c1 * c1);
        float y2 = wave_sum(a * a + bb * bb);
        float xy = wave_sum(c0 * a + c1 * bb);
        float nx  = 1.0f + 2.0f * xy + y2;
        float ny  = 1.0f - x2;
        float inv = 1.0f / fmaxf(1.0f + 2.0f * xy + x2 * y2, 1e-15f);
        zs[w][k][l]      = (nx * c0 + ny * a)  * inv;
        zs[w][k][l + 64] = (nx * c1 + ny * bb) * inv;
      }
    }
    asm volatile("s_waitcnt lgkmcnt(0)" ::: "memory");

    // v_i = sum_j R[i][j] z_j ; bounded unroll (full unroll spills: VGPR 256)
    float acc0[NS] = {}, acc1[NS] = {};
#pragma unroll 4
    for (int Jg = 0; Jg < 32; ++Jg) {
      f32x4 a0 = *(const f32x4*)&R[l * PADR + 4 * Jg];
      f32x4 a1 = *(const f32x4*)&R[(l + 64) * PADR + 4 * Jg];
#pragma unroll
      for (int k = 0; k < NS; ++k) {
        f32x4 zv = *(const f32x4*)&zs[w][k][4 * Jg];
#pragma unroll
        for (int m = 0; m < 4; ++m) {
          acc0[k] = fmaf(a0[m], zv[m], acc0[k]);
          acc1[k] = fmaf(a1[m], zv[m], acc1[k]);
        }
      }
    }
#pragma unroll
    for (int k = 0; k < NS; ++k) {
      if (k < kmax) {
        out[(size_t)bs[k] * D_DIM + l]      = acc0[k];
        out[(size_t)bs[k] * D_DIM + l + 64] = acc1[k];
      }
    }
  }

  // ---- grid-wide barrier; agent-scope fences for cross-XCD visibility of v
  __threadfence();
  grid.sync();
  __threadfence();

  n = min(totS, LCAP);

  // ---- phase B: w = R^T @ v; out = proj(mobius(proj(c_tgt), w))
  for (int s0 = (q * 4 + w) * NS; s0 < n; s0 += 32 * NS) {
    const int kmax = min(NS, n - s0);
    int bs[NS];
#pragma unroll
    for (int k = 0; k < NS; ++k) {
      if (k < kmax) {
        int b = slist[s0 + k];
        bs[k] = b;
        zs[w][k][l]      = out[(size_t)b * D_DIM + l];
        zs[w][k][l + 64] = out[(size_t)b * D_DIM + l + 64];
      }
    }
    asm volatile("s_waitcnt lgkmcnt(0)" ::: "memory");

    // w_i = sum_j R[j][i] v_j ; column reads = 2 lanes/bank (free); NS=2 shares R reads
    float acc0[NS] = {}, acc1[NS] = {};
#pragma unroll 8
    for (int j = 0; j < 128; ++j) {
      float r0 = R[j * PADR + l];
      float r1 = R[j * PADR + l + 64];
      float vj0 = zs[w][0][j];
      float vj1 = zs[w][1][j];
      acc0[0] = fmaf(r0, vj0, acc0[0]);
      acc1[0] = fmaf(r1, vj0, acc1[0]);
      acc0[1] = fmaf(r0, vj1, acc0[1]);
      acc1[1] = fmaf(r1, vj1, acc1[1]);
    }

#pragma unroll
    for (int k = 0; k < NS; ++k) {
      if (k < kmax) {
        int b = bs[k];
        int ti = tgt_idx[b];
        float c0 = centers[(size_t)ti * D_DIM + l];
        float c1 = centers[(size_t)ti * D_DIM + l + 64];
        float ncn = sqrtf(wave_sum(c0 * c0 + c1 * c1));
        if (ncn > MAXNORM) { float sc = MAXNORM / ncn; c0 *= sc; c1 *= sc; }

        float w0 = acc0[k], w1 = acc1[k];
        float x2 = wave_sum(c0 * c0 + c1 * c1);
        float y2 = wave_sum(w0 * w0 + w1 * w1);
        float xy = wave_sum(c0 * w0 + c1 * w1);
        float nx  = 1.0f + 2.0f * xy + y2;
        float ny  = 1.0f - x2;
        float inv = 1.0f / fmaxf(1.0f + 2.0f * xy + x2 * y2, 1e-15f);
        float o0 = (nx * c0 + ny * w0) * inv;
        float o1 = (nx * c1 + ny * w1) * inv;

        float no = sqrtf(wave_sum(o0 * o0 + o1 * o1));
        if (no > MAXNORM) { float sc = MAXNORM / no; o0 *= sc; o1 *= sc; }

        out[(size_t)b * D_DIM + l]      = o0;
        out[(size_t)b * D_DIM + l + 64] = o1;
      }
    }
  }
}

extern "C" void kernel_launch(void* const* d_in, const int* in_sizes, int n_in,
                              void* d_out, int out_size, void* d_ws, size_t ws_size,
                              hipStream_t stream) {
  const float* z_n     = (const float*)d_in[0];
  const float* centers = (const float*)d_in[1];
  const float* rot     = (const float*)d_in[2];
  const int*   src     = (const int*)d_in[3];
  const int*   tgt     = (const int*)d_in[4];
  float* out = (float*)d_out;
  int B = in_sizes[3];

  void* args[] = { (void*)&z_n, (void*)&centers, (void*)&rot,
                   (void*)&src, (void*)&tgt, (void*)&out, (void*)&B };
  hipLaunchCooperativeKernel((const void*)k_fused, dim3(NCHART * BPC), dim3(256),
                             args, 0, stream);
}

// Round 12
// 51.283 us; speedup vs baseline: 3.7519x; 3.7519x over previous
//
#include <hip/hip_runtime.h>
#include <math.h>

#define D_DIM   128
#define MAXNORM 0.99f

typedef float f32x4 __attribute__((ext_vector_type(4)));

__device__ __forceinline__ float wave_sum(float v) {
#pragma unroll
  for (int m = 32; m > 0; m >>= 1) v += __shfl_xor(v, m, 64);
  return v;
}

// One wave per sample. Fully sample-local: no lists, no barriers, no grid sync.
// R matrices read from global (rotations = 4MB -> L2-resident per XCD).
__global__ __launch_bounds__(256) void k_all(
    const float* __restrict__ z_n, const float* __restrict__ centers,
    const float* __restrict__ rot, const int* __restrict__ src_idx,
    const int* __restrict__ tgt_idx, float* __restrict__ out, int B)
{
  __shared__ float sbuf[4][D_DIM];   // per-wave broadcast buffer (2 KB)

  const int tid = threadIdx.x;
  const int w = tid >> 6, l = tid & 63;
  const int b = blockIdx.x * 4 + w;
  if (b >= B) return;                 // wave-uniform

  const int ct = tgt_idx[b];
  const int cs = src_idx[b];

  // ---- Mobius A on chunk ownership (lane owns components 2l, 2l+1) ----
  float2 z = ((const float2*)(z_n + (size_t)b * D_DIM))[l];
  float nz = sqrtf(wave_sum(z.x * z.x + z.y * z.y));
  if (nz > MAXNORM) { float sc = MAXNORM / nz; z.x *= sc; z.y *= sc; }

  float2 c = ((const float2*)(centers + (size_t)cs * D_DIM))[l];
  float ncn = sqrtf(wave_sum(c.x * c.x + c.y * c.y));
  if (ncn > MAXNORM) { float sc = MAXNORM / ncn; c.x *= sc; c.y *= sc; }
  c.x = -c.x; c.y = -c.y;             // x = -c_source

  {
    float x2 = wave_sum(c.x * c.x + c.y * c.y);
    float y2 = wave_sum(z.x * z.x + z.y * z.y);
    float xy = wave_sum(c.x * z.x + c.y * z.y);
    float nx  = 1.0f + 2.0f * xy + y2;
    float ny  = 1.0f - x2;
    float inv = 1.0f / fmaxf(1.0f + 2.0f * xy + x2 * y2, 1e-15f);
    float2 zg;
    zg.x = (nx * c.x + ny * z.x) * inv;
    zg.y = (nx * c.y + ny * z.y) * inv;
    ((float2*)sbuf[w])[l] = zg;       // sbuf[w][2l], [2l+1] (2 lanes/bank = free)
  }
  asm volatile("s_waitcnt lgkmcnt(0)" ::: "memory");

  // ---- A: v_i = sum_j Rt[i][j] zg_j ; lane computes rows l and l+64 ----
  // per-lane sequential 512B row stream (L1-line friendly), zg uniform from LDS
  const float* Rt = rot + (size_t)ct * D_DIM * D_DIM;
  float acc0 = 0.0f, acc1 = 0.0f;
#pragma unroll 4
  for (int J = 0; J < 32; ++J) {
    f32x4 r0 = *(const f32x4*)&Rt[l * D_DIM + 4 * J];
    f32x4 r1 = *(const f32x4*)&Rt[(l + 64) * D_DIM + 4 * J];
    f32x4 zv = *(const f32x4*)&sbuf[w][4 * J];
#pragma unroll
    for (int m = 0; m < 4; ++m) {
      acc0 = fmaf(r0[m], zv[m], acc0);
      acc1 = fmaf(r1[m], zv[m], acc1);
    }
  }
  // broadcast v (in-wave DS ordering: these writes issue after all zg reads)
  sbuf[w][l]      = acc0;
  sbuf[w][l + 64] = acc1;
  asm volatile("s_waitcnt lgkmcnt(0)" ::: "memory");

  // ---- B: w_i = sum_j Rs[j][i] v_j ; lane owns output chunk [2l, 2l+1] ----
  // coalesced float2 row reads (wave covers the full 512B row per instruction)
  const float* Rs = rot + (size_t)cs * D_DIM * D_DIM;
  float w0 = 0.0f, w1 = 0.0f;
#pragma unroll 4
  for (int J = 0; J < 32; ++J) {
    f32x4 vv = *(const f32x4*)&sbuf[w][4 * J];
#pragma unroll
    for (int m = 0; m < 4; ++m) {
      float2 rr = *(const float2*)&Rs[(4 * J + m) * D_DIM + 2 * l];
      w0 = fmaf(rr.x, vv[m], w0);
      w1 = fmaf(rr.y, vv[m], w1);
    }
  }

  // ---- Mobius B + final projection on chunk ownership ----
  float2 t = ((const float2*)(centers + (size_t)ct * D_DIM))[l];
  float nct = sqrtf(wave_sum(t.x * t.x + t.y * t.y));
  if (nct > MAXNORM) { float sc = MAXNORM / nct; t.x *= sc; t.y *= sc; }

  float x2 = wave_sum(t.x * t.x + t.y * t.y);
  float y2 = wave_sum(w0 * w0 + w1 * w1);
  float xy = wave_sum(t.x * w0 + t.y * w1);
  float nx  = 1.0f + 2.0f * xy + y2;
  float ny  = 1.0f - x2;
  float inv = 1.0f / fmaxf(1.0f + 2.0f * xy + x2 * y2, 1e-15f);
  float o0 = (nx * t.x + ny * w0) * inv;
  float o1 = (nx * t.y + ny * w1) * inv;

  float no = sqrtf(wave_sum(o0 * o0 + o1 * o1));
  if (no > MAXNORM) { float sc = MAXNORM / no; o0 *= sc; o1 *= sc; }

  float2 o; o.x = o0; o.y = o1;
  ((float2*)(out + (size_t)b * D_DIM))[l] = o;
}

extern "C" void kernel_launch(void* const* d_in, const int* in_sizes, int n_in,
                              void* d_out, int out_size, void* d_ws, size_t ws_size,
                              hipStream_t stream) {
  const float* z_n     = (const float*)d_in[0];
  const float* centers = (const float*)d_in[1];
  const float* rot     = (const float*)d_in[2];
  const int*   src     = (const int*)d_in[3];
  const int*   tgt     = (const int*)d_in[4];
  float* out = (float*)d_out;
  const int B = in_sizes[3];

  const int blocks = (B + 3) / 4;     // one wave (64 lanes) per sample
  k_all<<<dim3(blocks), dim3(256), 0, stream>>>(z_n, centers, rot, src, tgt, out, B);
}

// Round 14
// 51.261 us; speedup vs baseline: 3.7534x; 1.0004x over previous
//
#include <hip/hip_runtime.h>
#include <math.h>

#define D_DIM   128
#define MAXNORM 0.99f

typedef float f32x4 __attribute__((ext_vector_type(4)));

__device__ __forceinline__ float wave_sum(float v) {
#pragma unroll
  for (int m = 32; m > 0; m >>= 1) v += __shfl_xor(v, m, 64);
  return v;
}

// One wave per sample. Fully sample-local: no lists, no barriers, no grid sync.
// R matrices read from global (rotations = 4MB -> L2-resident per XCD).
__global__ __launch_bounds__(256) void k_all(
    const float* __restrict__ z_n, const float* __restrict__ centers,
    const float* __restrict__ rot, const int* __restrict__ src_idx,
    const int* __restrict__ tgt_idx, float* __restrict__ out, int B)
{
  __shared__ float sbuf[4][D_DIM];   // per-wave broadcast buffer (2 KB)

  const int tid = threadIdx.x;
  const int w = tid >> 6, l = tid & 63;
  const int b = blockIdx.x * 4 + w;
  if (b >= B) return;                 // wave-uniform

  const int ct = tgt_idx[b];
  const int cs = src_idx[b];

  // ---- Mobius A on chunk ownership (lane owns components 2l, 2l+1) ----
  float2 z = ((const float2*)(z_n + (size_t)b * D_DIM))[l];
  float nz = sqrtf(wave_sum(z.x * z.x + z.y * z.y));
  if (nz > MAXNORM) { float sc = MAXNORM / nz; z.x *= sc; z.y *= sc; }

  float2 c = ((const float2*)(centers + (size_t)cs * D_DIM))[l];
  float ncn = sqrtf(wave_sum(c.x * c.x + c.y * c.y));
  if (ncn > MAXNORM) { float sc = MAXNORM / ncn; c.x *= sc; c.y *= sc; }
  c.x = -c.x; c.y = -c.y;             // x = -c_source

  {
    float x2 = wave_sum(c.x * c.x + c.y * c.y);
    float y2 = wave_sum(z.x * z.x + z.y * z.y);
    float xy = wave_sum(c.x * z.x + c.y * z.y);
    float nx  = 1.0f + 2.0f * xy + y2;
    float ny  = 1.0f - x2;
    float inv = 1.0f / fmaxf(1.0f + 2.0f * xy + x2 * y2, 1e-15f);
    float2 zg;
    zg.x = (nx * c.x + ny * z.x) * inv;
    zg.y = (nx * c.y + ny * z.y) * inv;
    ((float2*)sbuf[w])[l] = zg;       // sbuf[w][2l], [2l+1]
  }
  asm volatile("s_waitcnt lgkmcnt(0)" ::: "memory");

  // ---- A: v = Rt @ zg, row-pair coalesced form ----
  // Per iteration the wave reads rows {2t, 2t+1} as ONE contiguous 1KB chunk
  // (16 line-probes, minimal) instead of 64 per-lane row streams (64 probes).
  // Lane: row = 2t + (l>>5), floats 4*(l&31)..+3; dot vs register zg chunk;
  // 5-step shfl_xor reduce within the 32-lane group -> v[row].
  const int half = l >> 5, quad = l & 31;
  const f32x4 zc = *(const f32x4*)&sbuf[w][4 * quad];   // zg chunk, regs, read once
  const float* Rt = rot + (size_t)ct * D_DIM * D_DIM;
#pragma unroll 8
  for (int t = 0; t < 64; ++t) {
    const int row = 2 * t + half;
    f32x4 rr = *(const f32x4*)&Rt[(size_t)row * D_DIM + 4 * quad];
    float p = fmaf(rr[3], zc[3], fmaf(rr[2], zc[2], fmaf(rr[1], zc[1], rr[0] * zc[0])));
    p += __shfl_xor(p, 1, 64);
    p += __shfl_xor(p, 2, 64);
    p += __shfl_xor(p, 4, 64);
    p += __shfl_xor(p, 8, 64);
    p += __shfl_xor(p, 16, 64);       // all lanes of the 32-group hold v[row]
    if (quad == 0) sbuf[w][row] = p;  // overwrite zg slot (zc already in regs)
  }
  asm volatile("s_waitcnt lgkmcnt(0)" ::: "memory");

  // ---- B: w_i = sum_j Rs[j][i] v_j ; lane owns output chunk [2l, 2l+1] ----
  // coalesced float2 row reads (wave covers the full 512B row per instruction)
  const float* Rs = rot + (size_t)cs * D_DIM * D_DIM;
  float w0 = 0.0f, w1 = 0.0f;
#pragma unroll 4
  for (int J = 0; J < 32; ++J) {
    f32x4 vv = *(const f32x4*)&sbuf[w][4 * J];
#pragma unroll
    for (int m = 0; m < 4; ++m) {
      float2 rr = *(const float2*)&Rs[(4 * J + m) * D_DIM + 2 * l];
      w0 = fmaf(rr.x, vv[m], w0);
      w1 = fmaf(rr.y, vv[m], w1);
    }
  }

  // ---- Mobius B + final projection on chunk ownership ----
  float2 t = ((const float2*)(centers + (size_t)ct * D_DIM))[l];
  float nct = sqrtf(wave_sum(t.x * t.x + t.y * t.y));
  if (nct > MAXNORM) { float sc = MAXNORM / nct; t.x *= sc; t.y *= sc; }

  float x2 = wave_sum(t.x * t.x + t.y * t.y);
  float y2 = wave_sum(w0 * w0 + w1 * w1);
  float xy = wave_sum(t.x * w0 + t.y * w1);
  float nx  = 1.0f + 2.0f * xy + y2;
  float ny  = 1.0f - x2;
  float inv = 1.0f / fmaxf(1.0f + 2.0f * xy + x2 * y2, 1e-15f);
  float o0 = (nx * t.x + ny * w0) * inv;
  float o1 = (nx * t.y + ny * w1) * inv;

  float no = sqrtf(wave_sum(o0 * o0 + o1 * o1));
  if (no > MAXNORM) { float sc = MAXNORM / no; o0 *= sc; o1 *= sc; }

  float2 o; o.x = o0; o.y = o1;
  ((float2*)(out + (size_t)b * D_DIM))[l] = o;
}

extern "C" void kernel_launch(void* const* d_in, const int* in_sizes, int n_in,
                              void* d_out, int out_size, void* d_ws, size_t ws_size,
                              hipStream_t stream) {
  const float* z_n     = (const float*)d_in[0];
  const float* centers = (const float*)d_in[1];
  const float* rot     = (const float*)d_in[2];
  const int*   src     = (const int*)d_in[3];
  const int*   tgt     = (const int*)d_in[4];
  float* out = (float*)d_out;
  const int B = in_sizes[3];

  const int blocks = (B + 3) / 4;     // one wave (64 lanes) per sample
  k_all<<<dim3(blocks), dim3(256), 0, stream>>>(z_n, centers, rot, src, tgt, out, B);
}

// Round 15
// 40.327 us; speedup vs baseline: 4.7711x; 1.2711x over previous
//
#include <hip/hip_runtime.h>
#include <math.h>

#define D_DIM   128
#define MAXNORM 0.99f

typedef float f32x4 __attribute__((ext_vector_type(4)));

__device__ __forceinline__ float wave_sum(float v) {
#pragma unroll
  for (int m = 32; m > 0; m >>= 1) v += __shfl_xor(v, m, 64);
  return v;
}

// One BLOCK (4 waves) per sample: 4096 blocks -> 32 waves/CU resident (vs 16
// at 1 wave/sample), and per-wave critical path cut ~4x. Mobius math verbatim
// from the verified round-12 kernel (chunk ownership: lane owns comps 2l,2l+1).
__global__ __launch_bounds__(256) void k_all(
    const float* __restrict__ z_n, const float* __restrict__ centers,
    const float* __restrict__ rot, const int* __restrict__ src_idx,
    const int* __restrict__ tgt_idx, float* __restrict__ out, int B)
{
  __shared__ float zbuf[D_DIM];   // z_global (transposed layout for stage A)
  __shared__ float vbuf[D_DIM];   // v = Rt @ zg
  __shared__ float wbuf[D_DIM];   // w = Rs^T @ v

  const int tid = threadIdx.x;
  const int w = tid >> 6, l = tid & 63;
  const int b = blockIdx.x;
  if (b >= B) return;

  const int ct = tgt_idx[b];
  const int cs = src_idx[b];

  // ---- Mobius A, replicated in all 4 waves (wave-local reductions, no sync) ----
  float2 z = ((const float2*)(z_n + (size_t)b * D_DIM))[l];
  float nz = sqrtf(wave_sum(z.x * z.x + z.y * z.y));
  if (nz > MAXNORM) { float sc = MAXNORM / nz; z.x *= sc; z.y *= sc; }

  float2 c = ((const float2*)(centers + (size_t)cs * D_DIM))[l];
  float ncn = sqrtf(wave_sum(c.x * c.x + c.y * c.y));
  if (ncn > MAXNORM) { float sc = MAXNORM / ncn; c.x *= sc; c.y *= sc; }
  c.x = -c.x; c.y = -c.y;             // x = -c_source

  {
    float x2 = wave_sum(c.x * c.x + c.y * c.y);
    float y2 = wave_sum(z.x * z.x + z.y * z.y);
    float xy = wave_sum(c.x * z.x + c.y * z.y);
    float nx  = 1.0f + 2.0f * xy + y2;
    float ny  = 1.0f - x2;
    float inv = 1.0f / fmaxf(1.0f + 2.0f * xy + x2 * y2, 1e-15f);
    float2 zg;
    zg.x = (nx * c.x + ny * z.x) * inv;
    zg.y = (nx * c.y + ny * z.y) * inv;
    if (w == 0) ((float2*)zbuf)[l] = zg;   // one wave publishes (all identical)
  }
  __syncthreads();

  // ---- Stage A: wave w computes v rows [32w, 32w+32), row-pair coalesced ----
  const int half = l >> 5, quad = l & 31;
  const f32x4 zc = *(const f32x4*)&zbuf[4 * quad];   // zg chunk in regs
  const float* Rt = rot + (size_t)ct * D_DIM * D_DIM;
#pragma unroll 4
  for (int t = 0; t < 16; ++t) {
    const int row = 32 * w + 2 * t + half;
    f32x4 rr = *(const f32x4*)&Rt[(size_t)row * D_DIM + 4 * quad];
    float p = fmaf(rr[3], zc[3], fmaf(rr[2], zc[2], fmaf(rr[1], zc[1], rr[0] * zc[0])));
    p += __shfl_xor(p, 1, 64);
    p += __shfl_xor(p, 2, 64);
    p += __shfl_xor(p, 4, 64);
    p += __shfl_xor(p, 8, 64);
    p += __shfl_xor(p, 16, 64);
    if (quad == 0) vbuf[row] = p;
  }
  __syncthreads();

  // ---- Stage B: w_i = sum_j Rs[j][i] v_j ; wave w owns outputs [32w,32w+32),
  // half-wave splits the j-range; one shfl_xor(32) combines. Per instr the wave
  // reads two 128B row segments (coalesced). ----
  const float* Rs = rot + (size_t)cs * D_DIM * D_DIM;
  const int i = 32 * w + quad;
  const int jb = 64 * half;
  float acc = 0.0f;
#pragma unroll 8
  for (int s = 0; s < 64; ++s) {
    acc = fmaf(Rs[(size_t)(jb + s) * D_DIM + i], vbuf[jb + s], acc);
  }
  acc += __shfl_xor(acc, 32, 64);
  if (l < 32) wbuf[i] = acc;
  __syncthreads();

  // ---- Mobius B + final projection, replicated; wave 0 stores ----
  float2 t = ((const float2*)(centers + (size_t)ct * D_DIM))[l];
  float nct = sqrtf(wave_sum(t.x * t.x + t.y * t.y));
  if (nct > MAXNORM) { float sc = MAXNORM / nct; t.x *= sc; t.y *= sc; }

  float2 wv = ((const float2*)wbuf)[l];
  float w0 = wv.x, w1 = wv.y;

  float x2 = wave_sum(t.x * t.x + t.y * t.y);
  float y2 = wave_sum(w0 * w0 + w1 * w1);
  float xy = wave_sum(t.x * w0 + t.y * w1);
  float nx  = 1.0f + 2.0f * xy + y2;
  float ny  = 1.0f - x2;
  float inv = 1.0f / fmaxf(1.0f + 2.0f * xy + x2 * y2, 1e-15f);
  float o0 = (nx * t.x + ny * w0) * inv;
  float o1 = (nx * t.y + ny * w1) * inv;

  float no = sqrtf(wave_sum(o0 * o0 + o1 * o1));
  if (no > MAXNORM) { float sc = MAXNORM / no; o0 *= sc; o1 *= sc; }

  if (w == 0) {
    float2 o; o.x = o0; o.y = o1;
    ((float2*)(out + (size_t)b * D_DIM))[l] = o;
  }
}

extern "C" void kernel_launch(void* const* d_in, const int* in_sizes, int n_in,
                              void* d_out, int out_size, void* d_ws, size_t ws_size,
                              hipStream_t stream) {
  const float* z_n     = (const float*)d_in[0];
  const float* centers = (const float*)d_in[1];
  const float* rot     = (const float*)d_in[2];
  const int*   src     = (const int*)d_in[3];
  const int*   tgt     = (const int*)d_in[4];
  float* out = (float*)d_out;
  const int B = in_sizes[3];

  k_all<<<dim3(B), dim3(256), 0, stream>>>(z_n, centers, rot, src, tgt, out, B);
}

// Round 18
// 33.722 us; speedup vs baseline: 5.7056x; 1.1959x over previous
//
#include <hip/hip_runtime.h>
#include <math.h>

#define D_DIM   128
#define MAXNORM 0.99f
#define MN2     (0.99f * 0.99f)

typedef float f32x4 __attribute__((ext_vector_type(4)));

// DPP-based reductions: VALU pipe only (shfl_xor would be ds_swizzle/bpermute
// on the LDS pipe, which round-15 counters showed is the bottleneck).
// NOTE: dpp_ctrl/row_mask must be integer constant expressions -> template.
template <int CTRL, int MASK>
__device__ __forceinline__ float dpp_add(float x) {
  int y = __builtin_amdgcn_update_dpp(0, __float_as_int(x), CTRL, MASK, 0xf, true);
  return x + __int_as_float(y);
}
// full 64-lane sum; returns wave-uniform total
__device__ __forceinline__ float dpp_sum64(float x) {
  x = dpp_add<0x111, 0xf>(x);   // row_shr:1
  x = dpp_add<0x112, 0xf>(x);   // row_shr:2
  x = dpp_add<0x114, 0xf>(x);   // row_shr:4
  x = dpp_add<0x118, 0xf>(x);   // row_shr:8
  x = dpp_add<0x142, 0xa>(x);   // row_bcast15 -> lanes 31,63 hold 32-group sums
  x = dpp_add<0x143, 0xc>(x);   // row_bcast31 -> lane 63 holds full sum
  return __int_as_float(__builtin_amdgcn_readlane(__float_as_int(x), 63));
}
// 32-lane-group sums: lane31 = sum(lanes 0..31), lane63 = sum(lanes 32..63)
__device__ __forceinline__ float dpp_sum32(float x) {
  x = dpp_add<0x111, 0xf>(x);
  x = dpp_add<0x112, 0xf>(x);
  x = dpp_add<0x114, 0xf>(x);
  x = dpp_add<0x118, 0xf>(x);
  x = dpp_add<0x142, 0xa>(x);
  return x;
}

// 2 samples per block, 2 waves per sample. All loads coalesced (1KB contiguous
// row-pairs), all reductions on VALU via DPP. 2048 blocks = 8/CU co-resident.
__global__ __launch_bounds__(256) void k_all(
    const float* __restrict__ z_n, const float* __restrict__ centers,
    const float* __restrict__ rot, const int* __restrict__ src_idx,
    const int* __restrict__ tgt_idx, float* __restrict__ out, int B)
{
  __shared__ float zbuf[2][D_DIM];      // z_global per sample slot
  __shared__ float vbuf[2][D_DIM];      // v = Rt @ zg
  __shared__ float pbuf[2][2][D_DIM];   // stage-B partials [p][s][i]

  const int tid = threadIdx.x;
  const int w = tid >> 6, l = tid & 63;
  const int s = w >> 1, p = w & 1;      // sample slot, wave-within-pair
  const int h = l >> 5, q = l & 31;
  int b = blockIdx.x * 2 + s;
  if (b >= B) b = B - 1;                // tail duplicates write identical values

  const int ct = tgt_idx[b];
  const int cs = src_idx[b];

  // ---- Mobius A (replicated in the pair; p==0 publishes). Lane owns comps 2l,2l+1.
  float2 z = ((const float2*)(z_n + (size_t)b * D_DIM))[l];
  float2 c = ((const float2*)(centers + (size_t)cs * D_DIM))[l];
  {
    float y2p = dpp_sum64(z.x * z.x + z.y * z.y);
    float x2p = dpp_sum64(c.x * c.x + c.y * c.y);
    float cz  = dpp_sum64(c.x * z.x + c.y * z.y);
    float sz = 1.0f, y2 = y2p;
    if (y2p > MN2) { sz = MAXNORM / sqrtf(y2p); y2 = MN2; }
    float sc = 1.0f, x2 = x2p;
    if (x2p > MN2) { sc = MAXNORM / sqrtf(x2p); x2 = MN2; }
    float xy  = -(sc * sz) * cz;        // x = -c_source
    float nx  = 1.0f + 2.0f * xy + y2;
    float ny  = 1.0f - x2;
    float inv = 1.0f / fmaxf(1.0f + 2.0f * xy + x2 * y2, 1e-15f);
    float2 zg;
    zg.x = (nx * (-sc * c.x) + ny * (sz * z.x)) * inv;
    zg.y = (nx * (-sc * c.y) + ny * (sz * z.y)) * inv;
    if (p == 0) ((float2*)zbuf[s])[l] = zg;
  }
  __syncthreads();

  // ---- Stage A: v = Rt @ zg. Wave p owns rows [64p,64p+64), 2 rows/iter.
  // Per instr: lanes read one contiguous 1KB row-pair (coalesced). DPP reduce.
  {
    const float* Rt = rot + (size_t)ct * D_DIM * D_DIM;
    const f32x4 zc = *(const f32x4*)&zbuf[s][4 * q];   // hoisted, regs
#pragma unroll 8
    for (int t = 0; t < 32; ++t) {
      const int r = 64 * p + 2 * t + h;
      f32x4 rr = *(const f32x4*)&Rt[(size_t)r * D_DIM + 4 * q];
      float pv = fmaf(rr[3], zc[3], fmaf(rr[2], zc[2], fmaf(rr[1], zc[1], rr[0] * zc[0])));
      pv = dpp_sum32(pv);               // lane31 -> row 64p+2t, lane63 -> +1
      if (q == 31) vbuf[s][r] = pv;
    }
  }
  __syncthreads();

  // ---- Stage B: w_i = sum_j Rs[j][i] v_j. Wave p owns j in [64p,64p+64),
  // 2 rows/iter (coalesced 1KB); lane accumulates cols 4q..4q+3; halves combine.
  {
    const float* Rs = rot + (size_t)cs * D_DIM * D_DIM;
    f32x4 acc = {0.0f, 0.0f, 0.0f, 0.0f};
#pragma unroll 8
    for (int t = 0; t < 32; ++t) {
      const int j = 64 * p + 2 * t + h;
      f32x4 rr = *(const f32x4*)&Rs[(size_t)j * D_DIM + 4 * q];
      float vj = vbuf[s][j];            // 2 distinct addrs/wave -> broadcast
      acc[0] = fmaf(rr[0], vj, acc[0]);
      acc[1] = fmaf(rr[1], vj, acc[1]);
      acc[2] = fmaf(rr[2], vj, acc[2]);
      acc[3] = fmaf(rr[3], vj, acc[3]);
    }
#pragma unroll
    for (int m = 0; m < 4; ++m) acc[m] += __shfl_xor(acc[m], 32, 64);
    if (h == 0) *(f32x4*)&pbuf[p][s][4 * q] = acc;
  }
  __syncthreads();

  // ---- Mobius B + final projection (replicated in pair; p==0 stores).
  {
    float2 w0 = ((const float2*)pbuf[0][s])[l];
    float2 w1 = ((const float2*)pbuf[1][s])[l];
    float2 wv; wv.x = w0.x + w1.x; wv.y = w0.y + w1.y;
    float2 t = ((const float2*)(centers + (size_t)ct * D_DIM))[l];

    float t2p = dpp_sum64(t.x * t.x + t.y * t.y);
    float w2  = dpp_sum64(wv.x * wv.x + wv.y * wv.y);
    float tw  = dpp_sum64(t.x * wv.x + t.y * wv.y);
    float st = 1.0f, x2 = t2p;
    if (t2p > MN2) { st = MAXNORM / sqrtf(t2p); x2 = MN2; }
    float xy  = st * tw;                // x = +c_target
    float nx  = 1.0f + 2.0f * xy + w2;
    float ny  = 1.0f - x2;
    float inv = 1.0f / fmaxf(1.0f + 2.0f * xy + x2 * w2, 1e-15f);
    float o0 = (nx * (st * t.x) + ny * wv.x) * inv;
    float o1 = (nx * (st * t.y) + ny * wv.y) * inv;

    float no2 = dpp_sum64(o0 * o0 + o1 * o1);
    if (no2 > MN2) { float sc = MAXNORM / sqrtf(no2); o0 *= sc; o1 *= sc; }

    if (p == 0) {
      float2 o; o.x = o0; o.y = o1;
      ((float2*)(out + (size_t)b * D_DIM))[l] = o;
    }
  }
}

extern "C" void kernel_launch(void* const* d_in, const int* in_sizes, int n_in,
                              void* d_out, int out_size, void* d_ws, size_t ws_size,
                              hipStream_t stream) {
  const float* z_n     = (const float*)d_in[0];
  const float* centers = (const float*)d_in[1];
  const float* rot     = (const float*)d_in[2];
  const int*   src     = (const int*)d_in[3];
  const int*   tgt     = (const int*)d_in[4];
  float* out = (float*)d_out;
  const int B = in_sizes[3];

  const int blocks = (B + 1) / 2;       // 2 samples per block
  k_all<<<dim3(blocks), dim3(256), 0, stream>>>(z_n, centers, rot, src, tgt, out, B);
}